// Round 11
// baseline (54.398 us; speedup 1.0000x reference)
//
#include <hip/hip_runtime.h>
#include <hip/hip_bf16.h>

// Round 11: R10 with the one-line fix — tail {m32,m33} lives at shorts 32,33
// of each mixed row (written by the group loop at c=13..33); R10 wrongly read
// it at +34. Everything else identical to R10:
//  - single barrier; 32 rows/wave (one W1f b128 read feeds two MFMAs)
//  - R6-verified bias-fold: c4 = mfma(a,bf, mfma(a_bias,b_bias,0))
//  - wbt packed {b1|W2, w32|w33} bf16 pairs in int2
// Verified varA layouts throughout (R2 diag, units=22).

#define B_ROWS 262144
#define DFEAT  181
#define BASICF 13
#define NG     21
#define HID    512
#define NT     1024
#define MSTRIDE 40                        // shorts per mixed row (80B)
#define ROWS_PER_BLOCK 512
#define NBLK   (B_ROWS / ROWS_PER_BLOCK)  // 512

typedef __attribute__((ext_vector_type(8))) short short8;
typedef __attribute__((ext_vector_type(4))) float float4_t;

__device__ __forceinline__ short f2bf(float f) {
    union { float f; unsigned u; } v; v.f = f;
    unsigned r = (v.u + 0x7FFFu + ((v.u >> 16) & 1u)) >> 16;  // RNE
    return (short)r;
}
__device__ __forceinline__ float bfhi2f(unsigned u) {  // bf16 in high 16 bits
    union { unsigned u; float f; } v; v.u = u;
    return v.f;
}
__device__ __forceinline__ float sigm(float x) { return 1.0f / (1.0f + __expf(-x)); }

// 16B load at 4B alignment (group region starts at float index 13)
__device__ __forceinline__ float4_t load4u(const float* p) {
    float4_t v;
    __builtin_memcpy(&v, p, 16);
    return v;
}

__global__ __launch_bounds__(NT) void fused_mfma_kernel(
    const float* __restrict__ data, const float* __restrict__ gW,
    const float* __restrict__ gb, const float* __restrict__ W1,
    const float* __restrict__ b1, const float* __restrict__ W2,
    const float* __restrict__ b2, float* __restrict__ out)
{
    // LDS: 32768 + 4096 + 40960 = 77824 B -> 2 blocks/CU
    __shared__ __align__(16) short W1f[32 * 64 * 8];       // B-frags k=0..31 (verified layout)
    __shared__ __align__(8)  int   wbt2[HID * 2];          // {b1|W2<<16, w32|w33<<16} bf16 bits
    __shared__ __align__(16) short mixed[ROWS_PER_BLOCK * MSTRIDE];
    // per row: shorts 0..33 = features bf16 (32,33 = tail {m32,m33}); 34..39 pad

    const int tid  = threadIdx.x;
    const int wave = tid >> 6;
    const int lane = tid & 63;
    const int lg   = lane >> 4;   // 0..3
    const int li   = lane & 15;

    // ---- stage W1f (verbatim verified mapping) ----
    for (int idx = tid; idx < 32 * HID; idx += NT) {
        int k = idx >> 9, c = idx & 511;
        int t = c >> 4, ci = c & 15;
        int l = ((k >> 3) << 4) + ci;
        int j = k & 7;
        W1f[(t * 64 + l) * 8 + j] = f2bf(W1[k * HID + c]);
    }
    if (tid < HID) {
        int c = tid;
        unsigned pb  = (unsigned short)f2bf(b1[c]);
        unsigned pw2 = (unsigned short)f2bf(W2[c]);
        unsigned pa  = (unsigned short)f2bf(W1[32 * HID + c]);
        unsigned pbb = (unsigned short)f2bf(W1[33 * HID + c]);
        wbt2[c * 2 + 0] = (int)(pb | (pw2 << 16));   // b1 low, W2 high
        wbt2[c * 2 + 1] = (int)(pa | (pbb << 16));   // w32 low, w33 high
    }

    // gW/gb in registers: lane l holds gW-float4 #l (l<42) and gb[l>>1]
    float4_t gwv = {0.f, 0.f, 0.f, 0.f};
    float gbv = 0.f;
    if (lane < 42) {
        gwv = ((const float4_t*)gW)[lane];
        gbv = gb[lane >> 1];
    }
    const float b2v = b2[0];
    const int blk_row0 = blockIdx.x * ROWS_PER_BLOCK;

    // ---- build: wave builds rows [wave*32, wave*32+32) (R8/R9-verified scheme) ----
    #pragma unroll 4
    for (int rr = 0; rr < 32; ++rr) {
        const int row = wave * 32 + rr;
        const float* dr = data + (size_t)(blk_row0 + row) * DFEAT;
        if (lane < 42) {
            float4_t x = load4u(dr + BASICF + lane * 4);
            float p = fmaf(x[0], gwv[0],
                      fmaf(x[1], gwv[1],
                      fmaf(x[2], gwv[2], x[3] * gwv[3])));
            p += __shfl_xor(p, 1, 64);      // pair (2g,2g+1) -> full 8-wide dot
            if ((lane & 1) == 0) {
                int g = lane >> 1;           // 0..20
                float v = sigm(p + gbv);
                mixed[row * MSTRIDE + BASICF + g] = f2bf(v);  // c=13..33 (32,33 = tail)
            }
        } else if (lane >= 43 && lane < 56) {
            int c = lane - 43;               // 0..12
            mixed[row * MSTRIDE + c] = f2bf(dr[c]);
        }
    }
    __syncthreads();   // staging + build complete; MFMA phase is barrier-free

    // ---- MFMA phase: rows r0..r0+15 (lo) and r0+16..r0+31 (hi) ----
    const int r0 = wave * 32;
    // A-frags (verified): lane l, reg j -> A[row=l&15][k=(l>>4)*8+j]
    short8 a_lo = *(const short8*)&mixed[(r0 + li) * MSTRIDE + lg * 8];
    short8 a_hi = *(const short8*)&mixed[(r0 + 16 + li) * MSTRIDE + lg * 8];
    // bias A-frags (R6-verified fold): lg0 lanes: reg0=m32, reg1=m33, reg2=1.0
    short8 ab_lo, ab_hi;
    {
        int mt_lo = *(const int*)&mixed[(r0 + li) * MSTRIDE + 32];       // {m32,m33}
        int mt_hi = *(const int*)&mixed[(r0 + 16 + li) * MSTRIDE + 32];  // {m32,m33}
        union { int i[4]; short8 s; } ua;
        ua.i[0] = (lg == 0) ? mt_lo : 0;
        ua.i[1] = (lg == 0) ? 0x00003F80 : 0;  // {1.0bf16, 0}
        ua.i[2] = 0; ua.i[3] = 0;
        ab_lo = ua.s;
        ua.i[0] = (lg == 0) ? mt_hi : 0;
        ab_hi = ua.s;
    }

    float4_t acc_lo = {0.f, 0.f, 0.f, 0.f};
    float4_t acc_hi = {0.f, 0.f, 0.f, 0.f};
    const float4_t z4 = {0.f, 0.f, 0.f, 0.f};
    for (int t = 0; t < 32; ++t) {
        short8 bf = *(const short8*)&W1f[(t * 64 + lane) * 8];
        int2 wv = ((const int2*)wbt2)[t * 16 + li];
        // bias B-frag: lg0 lanes: reg0=w32, reg1=w33, reg2=b1
        union { int i[4]; short8 s; } ub;
        ub.i[0] = (lg == 0) ? wv.y : 0;              // {w32, w33}
        ub.i[1] = (lg == 0) ? (wv.x & 0xffff) : 0;   // {b1, 0}
        ub.i[2] = 0; ub.i[3] = 0;
        float4_t c_lo = __builtin_amdgcn_mfma_f32_16x16x32_bf16(ab_lo, ub.s, z4, 0, 0, 0);
        float4_t c_hi = __builtin_amdgcn_mfma_f32_16x16x32_bf16(ab_hi, ub.s, z4, 0, 0, 0);
        c_lo = __builtin_amdgcn_mfma_f32_16x16x32_bf16(a_lo, bf, c_lo, 0, 0, 0);
        c_hi = __builtin_amdgcn_mfma_f32_16x16x32_bf16(a_hi, bf, c_hi, 0, 0, 0);
        // C-frag (verified): lane l holds C[row=(l>>4)*4+j][col=t*16+(l&15)]
        float w2f = bfhi2f((unsigned)wv.x & 0xffff0000u);
        #pragma unroll
        for (int j = 0; j < 4; ++j) {
            acc_lo[j] = fmaf(fmaxf(c_lo[j], 0.f), w2f, acc_lo[j]);
            acc_hi[j] = fmaf(fmaxf(c_hi[j], 0.f), w2f, acc_hi[j]);
        }
    }
    // reduce layer-2 partials across the 16 col-lanes (verified)
    #pragma unroll
    for (int m = 1; m < 16; m <<= 1) {
        #pragma unroll
        for (int j = 0; j < 4; ++j) {
            acc_lo[j] += __shfl_xor(acc_lo[j], m, 64);
            acc_hi[j] += __shfl_xor(acc_hi[j], m, 64);
        }
    }
    if (li == 0) {
        #pragma unroll
        for (int j = 0; j < 4; ++j) {
            out[blk_row0 + r0 + lg * 4 + j]      = sigm(acc_lo[j] + b2v);
            out[blk_row0 + r0 + 16 + lg * 4 + j] = sigm(acc_hi[j] + b2v);
        }
    }
}

extern "C" void kernel_launch(void* const* d_in, const int* in_sizes, int n_in,
                              void* d_out, int out_size, void* d_ws, size_t ws_size,
                              hipStream_t stream) {
    (void)in_sizes; (void)n_in; (void)out_size; (void)d_ws; (void)ws_size;
    const float* data = (const float*)d_in[0];
    const float* gW   = (const float*)d_in[1];
    const float* gb   = (const float*)d_in[2];
    const float* W1   = (const float*)d_in[3];
    const float* b1   = (const float*)d_in[4];
    const float* W2   = (const float*)d_in[5];
    const float* b2   = (const float*)d_in[6];
    float* out = (float*)d_out;
    fused_mfma_kernel<<<dim3(NBLK), dim3(NT), 0, stream>>>(data, gW, gb, W1, b1, W2, b2, out);
}